// Round 11
// baseline (335.794 us; speedup 1.0000x reference)
//
#include <hip/hip_runtime.h>
#include <hip/hip_fp16.h>
#include <string.h>

namespace {
constexpr int kN = 50000;
constexpr int kD = 256;
constexpr int kPos = 32;
constexpr int kNeg = 20;
constexpr int kGathers = kPos + kNeg;  // 52
constexpr float kEps = 1e-15f;
constexpr int kSlots = kPos / 4 + kNeg / 4;  // 13 (legacy path)
constexpr int kCompactBlocks = (kN + 255) / 256;   // 196
constexpr int kConvertBlocks = kN * kD / 8 / 256;  // 6250
constexpr int kSliceD = 32;                        // dims per slice
constexpr int kNSlices = kD / kSliceD;             // 8 == #XCDs
constexpr size_t kSliceBytes = (size_t)kN * kSliceD;  // 1.6 MB

typedef float floatx2 __attribute__((ext_vector_type(2)));

#if __has_builtin(__builtin_amdgcn_cvt_pk_f32_fp8)
constexpr bool kHwCvtPk = true;
constexpr bool kHwCvt1 = false;
#elif __has_builtin(__builtin_amdgcn_cvt_f32_fp8)
constexpr bool kHwCvtPk = false;
constexpr bool kHwCvt1 = true;
#else
constexpr bool kHwCvtPk = false;
constexpr bool kHwCvt1 = false;
#endif
// software-decode fallback yields value*2^-8, so own must be pre-scaled by 256
constexpr float kOwnScale = (kHwCvtPk || kHwCvt1) ? 1.f : 256.f;

// ---------- fp8 e4m3fn encode ----------
__device__ __forceinline__ uint enc1(float x) {
    const __half hh = __float2half(x * 0.00390625f);  // x * 2^-8, HW RNE
    unsigned short t;
    memcpy(&t, &hh, 2);
    const uint s = ((uint)t >> 8) & 0x80u;
    uint mag = (uint)t & 0x7fffu;
    mag = mag + 0x3fu + ((mag >> 7) & 1u);  // RNE 10->3 bit mantissa
    uint u = mag >> 7;
    if (u > 0x7eu) u = 0x7eu;
    return s | u;
}

__device__ __forceinline__ uint enc4(const float4 a) {
#if __has_builtin(__builtin_amdgcn_cvt_pk_fp8_f32)
    int u = __builtin_amdgcn_cvt_pk_fp8_f32(a.x, a.y, 0, false);    // bytes 0,1
    u = __builtin_amdgcn_cvt_pk_fp8_f32(a.z, a.w, u, true);         // bytes 2,3
    return (uint)u;
#else
    return enc1(a.x) | (enc1(a.y) << 8) | (enc1(a.z) << 16) | (enc1(a.w) << 24);
#endif
}

__device__ __forceinline__ float dec_h(uint h) {
    __half hh;
    const unsigned short t = (unsigned short)h;
    memcpy(&hh, &t, 2);
    return __half2float(hh);
}

// Decode 4 packed e4m3 bytes, accumulate dot with o.x..o.w into d.
__device__ __forceinline__ void dq4f(uint u, const float4& o, float& d) {
#if __has_builtin(__builtin_amdgcn_cvt_pk_f32_fp8)
    const floatx2 lo = __builtin_amdgcn_cvt_pk_f32_fp8((int)u, false);  // bytes 0,1
    const floatx2 hi = __builtin_amdgcn_cvt_pk_f32_fp8((int)u, true);   // bytes 2,3
    d = fmaf(lo.x, o.x, d);
    d = fmaf(lo.y, o.y, d);
    d = fmaf(hi.x, o.z, d);
    d = fmaf(hi.y, o.w, d);
#elif __has_builtin(__builtin_amdgcn_cvt_f32_fp8)
    d = fmaf(__builtin_amdgcn_cvt_f32_fp8((int)u, 0), o.x, d);
    d = fmaf(__builtin_amdgcn_cvt_f32_fp8((int)u, 1), o.y, d);
    d = fmaf(__builtin_amdgcn_cvt_f32_fp8((int)u, 2), o.z, d);
    d = fmaf(__builtin_amdgcn_cvt_f32_fp8((int)u, 3), o.w, d);
#else
    const float v0 = dec_h(((u << 8) & 0x8000u) | ((u << 7) & 0x3f80u));
    const float v1 = dec_h((u & 0x8000u) | ((u >> 1) & 0x3f80u));
    const float v2 = dec_h(((u >> 8) & 0x8000u) | ((u >> 9) & 0x3f80u));
    const float v3 = dec_h(((u >> 16) & 0x8000u) | ((u >> 17) & 0x3f80u));
    d = fmaf(v0, o.x, d);
    d = fmaf(v1, o.y, d);
    d = fmaf(v2, o.z, d);
    d = fmaf(v3, o.w, d);
#endif
}

__device__ __forceinline__ void dq4(uint u, const float* o, float& d) {
    const float4 f = {o[0], o[1], o[2], o[3]};
    dq4f(u, f, d);
}

// ---------- fused prep: compaction + SLICED fp8 convert + out zeroing ----------
// Sliced table layout: tbl[q*1.6MB + n*32 + j], q = dim/32 slice. Dest linear
// in tid (coalesced 8B stores); source emb reads are also coalesced (the 32
// consecutive tids covering row n read its 1 KB contiguously).
__global__ __launch_bounds__(256) void prep_kernel(const float* __restrict__ emb,
                                                   uchar* __restrict__ tbl,
                                                   const int* __restrict__ rmask,
                                                   int* __restrict__ list,
                                                   float* __restrict__ acc,
                                                   float* __restrict__ out) {
    const int bid = blockIdx.x;
    if (bid < kCompactBlocks) {
        if (bid == 0 && threadIdx.x == 0) out[0] = 0.f;
        const int n = bid * 256 + threadIdx.x;
        if (n < kN && rmask[n]) {
            const int p = atomicAdd(reinterpret_cast<unsigned*>(&acc[2]), 1u);
            list[p] = n;
        }
    } else {
        const size_t a = ((size_t)(bid - kCompactBlocks) * 256 + threadIdx.x) * 8;
        const int q = (int)(a / kSliceBytes);
        const size_t r = a % kSliceBytes;
        const int n = (int)(r / kSliceD);
        const int j = (int)(r % kSliceD);  // 0,8,16,24
        const float* src = emb + (size_t)n * kD + q * kSliceD + j;
        const float4 f0 = reinterpret_cast<const float4*>(src)[0];
        const float4 f1 = reinterpret_cast<const float4*>(src)[1];
        uint2 o;
        o.x = enc4(f0);
        o.y = enc4(f1);
        *reinterpret_cast<uint2*>(tbl + a) = o;
    }
}

// ---------- Phase A: XCD-pinned partial dots ----------
// Slice q is processed ONLY by blocks with blockIdx%8==q, which the HW
// round-robin dispatcher places on XCD q -> each XCD gathers from its own
// 1.6 MB slice, L2-resident. Fills drop 102 MB -> ~13 MB (no 8x replication).
// Wave layout: 8 gathers in parallel (8 lanes each: lane&7 = dim-quad).
// Partials accumulate into dots[i*52+gi] via atomicAdd (f32).
// Correctness does NOT depend on the XCD mapping (only locality does).
__global__ __launch_bounds__(256) void partial_dots(
    const float* __restrict__ emb,
    const uchar* __restrict__ tbl,
    const int* __restrict__ nbr,
    const int* __restrict__ neg,
    const int* __restrict__ list,
    const float* __restrict__ acc,
    float* __restrict__ dots) {
    const int q = blockIdx.x & 7;    // slice == XCD (perf heuristic only)
    const int bs = blockIdx.x >> 3;  // block index within slice
    const int wave = threadIdx.x >> 6;
    const int lane = threadIdx.x & 63;
    const int g8 = lane >> 3;  // gather group 0..7
    const int l8 = lane & 7;   // dim quad 0..7 (16 of 32 dims? no: 8x4=32)
    const int cnt_active = reinterpret_cast<const int*>(acc)[2];
    const uchar* slice = tbl + (size_t)q * kSliceBytes;
    const int wave_id = bs * 4 + wave;
    const int stride = (gridDim.x >> 3) * 4;  // waves per slice

    for (int i = wave_id; i < cnt_active; i += stride) {
        const int n = list[i];
        // own dims for this lane: [q*32 + l8*4, +4), exact fp32
        float4 own = *reinterpret_cast<const float4*>(
            emb + (size_t)n * kD + q * kSliceD + l8 * 4);
        own.x *= kOwnScale;
        own.y *= kOwnScale;
        own.z *= kOwnScale;
        own.w *= kOwnScale;
        const int* nrow = nbr + (size_t)n * kPos;
        const int* grow = neg + (size_t)n * kNeg;
        float* drow = dots + (size_t)i * kGathers;
#pragma unroll
        for (int k = 0; k < 7; ++k) {
            const int gi = k * 8 + g8;
            const int gic = gi < kGathers ? gi : 0;  // clamp pad lanes (k=6)
            const int idx = gic < kPos ? nrow[gic] : grow[gic - kPos];
            const uint u = *reinterpret_cast<const uint*>(
                slice + (size_t)idx * kSliceD + l8 * 4);
            float d = 0.f;
            dq4f(u, own, d);
            d += __shfl_xor(d, 4);
            d += __shfl_xor(d, 2);
            d += __shfl_xor(d, 1);
            if (l8 == 0 && gi < kGathers) atomicAdd(&drow[gi], d);
        }
    }
}

// ---------- Phase B: per-row loss from summed dots ----------
// One wave per active row; lane s handles slot s (s < 52).
__global__ __launch_bounds__(256) void finish_loss(
    const int* __restrict__ nbrm,
    const int* __restrict__ list,
    const float* __restrict__ acc,
    const float* __restrict__ dots,
    float* __restrict__ out) {
    __shared__ float s_num[4];
    const int wave = threadIdx.x >> 6;
    const int lane = threadIdx.x & 63;
    const int cnt_active = reinterpret_cast<const int*>(acc)[2];
    const int i = blockIdx.x * 4 + wave;
    float num = 0.f;

    if (i < cnt_active) {
        const int n = list[i];
        float pos_sum = 0.f, neg_sum = 0.f, cnt = 0.f;
        if (lane < kGathers) {
            const float d = dots[(size_t)i * kGathers + lane];
            const float sg = 1.f / (1.f + __expf(-d));
            if (lane < kPos) {
                const float m = (float)nbrm[(size_t)n * kPos + lane];
                pos_sum = -__logf(sg + kEps) * m;
                cnt = m;
            } else {
                neg_sum = -__logf(1.f - sg + kEps);
            }
        }
#pragma unroll
        for (int o = 32; o >= 1; o >>= 1) {
            pos_sum += __shfl_xor(pos_sum, o);
            neg_sum += __shfl_xor(neg_sum, o);
            cnt += __shfl_xor(cnt, o);
        }
        if (cnt > 0.f) num = pos_sum / cnt + neg_sum / (float)kNeg;
        // cnt==0 -> NaN row in reference -> replaced by 0 -> contributes 0
    }

    if (lane == 0) s_num[wave] = num;
    __syncthreads();
    if (threadIdx.x == 0) {
        const float v = s_num[0] + s_num[1] + s_num[2] + s_num[3];
        if (v != 0.f) atomicAdd(out, v / (float)cnt_active);
    }
}

// ---------- legacy single-kernel fp8 path (mid-size ws fallback) ----------
__global__ __launch_bounds__(256) void convert_fp8_flat(const float* __restrict__ emb,
                                                        uint* __restrict__ tbl) {
    const size_t i = ((size_t)blockIdx.x * 256 + threadIdx.x) * 8;
    const float4* src = reinterpret_cast<const float4*>(emb + i);
    uint2 o;
    o.x = enc4(src[0]);
    o.y = enc4(src[1]);
    reinterpret_cast<uint2*>(tbl)[i / 8] = o;
}

__global__ __launch_bounds__(256) void compact_kernel(const int* __restrict__ rmask,
                                                      int* __restrict__ list,
                                                      float* __restrict__ acc) {
    const int n = blockIdx.x * 256 + threadIdx.x;
    if (n < kN && rmask[n]) {
        const int p = atomicAdd(reinterpret_cast<unsigned*>(&acc[2]), 1u);
        list[p] = n;
    }
}

__global__ __launch_bounds__(256) void row_loss_fp8(
    const float* __restrict__ emb,
    const uchar* __restrict__ tblb,
    const int* __restrict__ nbr,
    const int* __restrict__ nbrm,
    const int* __restrict__ neg,
    const int* __restrict__ list,
    float* __restrict__ acc) {
    __shared__ float s_num[4];
    const int wave = threadIdx.x >> 6;
    const int lane = threadIdx.x & 63;
    const int g = lane >> 4;
    const int t = lane & 15;
    const uint lane_off = (uint)t * 16u;

    const int cnt_active = reinterpret_cast<const int*>(acc)[2];
    const int i = blockIdx.x * 4 + wave;
    float num = 0.f;

    if (i < cnt_active) {
        const int n = list[i];
        const float4* erow = reinterpret_cast<const float4*>(emb + (size_t)n * kD);
        float own[16];
#pragma unroll
        for (int j = 0; j < 4; ++j) {
            const float4 f = erow[4 * t + j];
            own[4 * j + 0] = f.x * kOwnScale;
            own[4 * j + 1] = f.y * kOwnScale;
            own[4 * j + 2] = f.z * kOwnScale;
            own[4 * j + 3] = f.w * kOwnScale;
        }
        const int* nrow = nbr + (size_t)n * kPos;
        const int* mrow = nbrm + (size_t)n * kPos;
        const int* grow = neg + (size_t)n * kNeg;
        uint off[kSlots];
        float w[kPos / 4];
        float cnt = 0.f;
#pragma unroll
        for (int s = 0; s < kPos / 4; ++s) {
            off[s] = ((uint)nrow[s * 4 + g] << 8) + lane_off;
            const float mf = (float)mrow[s * 4 + g];
            w[s] = mf;
            cnt += mf;
        }
#pragma unroll
        for (int s = 0; s < kNeg / 4; ++s)
            off[kPos / 4 + s] = ((uint)grow[s * 4 + g] << 8) + lane_off;

        float pos_sum = 0.f, neg_sum = 0.f;
        uint4 u = *reinterpret_cast<const uint4*>(tblb + off[0]);
#pragma unroll
        for (int s = 0; s < kSlots; ++s) {
            const uint4 uc = u;
            if (s + 1 < kSlots)
                u = *reinterpret_cast<const uint4*>(tblb + off[s + 1]);
            float d = 0.f;
            dq4(uc.x, own + 0, d);
            dq4(uc.y, own + 4, d);
            dq4(uc.z, own + 8, d);
            dq4(uc.w, own + 12, d);
            d += __shfl_xor(d, 8);
            d += __shfl_xor(d, 4);
            d += __shfl_xor(d, 2);
            d += __shfl_xor(d, 1);
            const float sg = 1.f / (1.f + __expf(-d));
            if (s < kPos / 4) {
                pos_sum += -__logf(sg + kEps) * w[s];
            } else {
                neg_sum += -__logf(1.f - sg + kEps);
            }
        }
        pos_sum += __shfl_xor(pos_sum, 16);
        pos_sum += __shfl_xor(pos_sum, 32);
        neg_sum += __shfl_xor(neg_sum, 16);
        neg_sum += __shfl_xor(neg_sum, 32);
        cnt += __shfl_xor(cnt, 16);
        cnt += __shfl_xor(cnt, 32);
        if (cnt > 0.f) num = pos_sum / cnt + neg_sum / (float)kNeg;
    }

    if (lane == 0) s_num[wave] = num;
    __syncthreads();
    if (threadIdx.x == 0) {
        const float v = s_num[0] + s_num[1] + s_num[2] + s_num[3];
        if (v != 0.f) atomicAdd(&acc[0], v);
    }
}

__global__ void finalize_kernel(const float* __restrict__ acc, float* __restrict__ out) {
    out[0] = acc[0] / (float)reinterpret_cast<const int*>(acc)[2];
}

// ---------- fp32 direct fallback (tiny ws; UNCHANGED) ----------
__global__ __launch_bounds__(256) void row_loss_f32(
    const float* __restrict__ emb,
    const int* __restrict__ nbr,
    const int* __restrict__ nbrm,
    const int* __restrict__ neg,
    const int* __restrict__ rmask,
    float* __restrict__ acc) {
    __shared__ float s_num[4];
    __shared__ float s_den[4];
    const int wave = threadIdx.x >> 6;
    const int lane = threadIdx.x & 63;
    const int n = blockIdx.x * 4 + wave;
    const int g = lane >> 4;
    const int t = lane & 15;

    const float4* erow = reinterpret_cast<const float4*>(emb + (size_t)n * kD);
    float4 own4[4];
#pragma unroll
    for (int j = 0; j < 4; ++j) own4[j] = erow[j * 16 + t];

    const int* nrow = nbr + (size_t)n * kPos;
    const int* mrow = nbrm + (size_t)n * kPos;
    const int* grow = neg + (size_t)n * kNeg;

    float pos_sum = 0.f, neg_sum = 0.f, cnt = 0.f;
#pragma unroll
    for (int it = 0; it < kPos / 4; ++it) {
        const int idx = nrow[it * 4 + g];
        const float mf = (float)mrow[it * 4 + g];
        cnt += mf;
        const float4* brow = reinterpret_cast<const float4*>(emb + (size_t)idx * kD);
        float d = 0.f;
#pragma unroll
        for (int j = 0; j < 4; ++j) {
            const float4 b = brow[j * 16 + t];
            const float4 a = own4[j];
            d += a.x * b.x + a.y * b.y + a.z * b.z + a.w * b.w;
        }
        d += __shfl_xor(d, 8);
        d += __shfl_xor(d, 4);
        d += __shfl_xor(d, 2);
        d += __shfl_xor(d, 1);
        const float s = 1.f / (1.f + __expf(-d));
        pos_sum += -__logf(s + kEps) * mf;
    }
#pragma unroll
    for (int it = 0; it < kNeg / 4; ++it) {
        const int idx = grow[it * 4 + g];
        const float4* brow = reinterpret_cast<const float4*>(emb + (size_t)idx * kD);
        float d = 0.f;
#pragma unroll
        for (int j = 0; j < 4; ++j) {
            const float4 b = brow[j * 16 + t];
            const float4 a = own4[j];
            d += a.x * b.x + a.y * b.y + a.z * b.z + a.w * b.w;
        }
        d += __shfl_xor(d, 8);
        d += __shfl_xor(d, 4);
        d += __shfl_xor(d, 2);
        d += __shfl_xor(d, 1);
        const float s = 1.f / (1.f + __expf(-d));
        neg_sum += -__logf(1.f - s + kEps);
    }

    pos_sum += __shfl_xor(pos_sum, 16);
    pos_sum += __shfl_xor(pos_sum, 32);
    neg_sum += __shfl_xor(neg_sum, 16);
    neg_sum += __shfl_xor(neg_sum, 32);
    cnt += __shfl_xor(cnt, 16);
    cnt += __shfl_xor(cnt, 32);

    float num = 0.f;
    if (cnt > 0.f) num = pos_sum / cnt + neg_sum / (float)kNeg;
    const float rmf = (float)rmask[n];

    if (lane == 0) {
        s_num[wave] = num * rmf;
        s_den[wave] = rmf;
    }
    __syncthreads();
    if (threadIdx.x == 0) {
        atomicAdd(&acc[0], s_num[0] + s_num[1] + s_num[2] + s_num[3]);
        atomicAdd(&acc[1], s_den[0] + s_den[1] + s_den[2] + s_den[3]);
    }
}

__global__ void finalize_f32(const float* __restrict__ acc, float* __restrict__ out) {
    out[0] = acc[0] / acc[1];
}
}  // namespace

extern "C" void kernel_launch(void* const* d_in, const int* in_sizes, int n_in,
                              void* d_out, int out_size, void* d_ws, size_t ws_size,
                              hipStream_t stream) {
    const float* emb = (const float*)d_in[0];
    const int* nbr = (const int*)d_in[1];
    const int* nbrm = (const int*)d_in[2];
    const int* neg = (const int*)d_in[3];
    const int* rmask = (const int*)d_in[4];
    float* acc = (float*)d_ws;  // [0]=num, [1]=den, [2]=active count

    const size_t tbl_bytes = (size_t)kN * kD;                      // 12.8 MB
    const size_t list_bytes = (size_t)kN * sizeof(int);            // 0.2 MB
    const size_t dots_bytes = (size_t)kN * kGathers * sizeof(float);  // 10.4 MB

    if (ws_size >= 256 + dots_bytes + tbl_bytes + list_bytes) {
        // ---- XCD-sliced two-phase path ----
        float* dots = (float*)((char*)d_ws + 256);
        uchar* tbl = (uchar*)d_ws + 256 + dots_bytes;
        int* list = (int*)((char*)d_ws + 256 + dots_bytes + tbl_bytes);
        hipMemsetAsync(d_ws, 0, 256 + dots_bytes, stream);
        prep_kernel<<<kCompactBlocks + kConvertBlocks, 256, 0, stream>>>(
            emb, tbl, rmask, list, acc, (float*)d_out);
        partial_dots<<<2048, 256, 0, stream>>>(emb, tbl, nbr, neg, list, acc, dots);
        finish_loss<<<(kN + 3) / 4, 256, 0, stream>>>(nbrm, list, acc, dots,
                                                      (float*)d_out);
    } else if (ws_size >= 256 + tbl_bytes + list_bytes) {
        // ---- legacy flat-table fp8 path ----
        uint* tbl = (uint*)((char*)d_ws + 256);
        int* list = (int*)((char*)d_ws + 256 + tbl_bytes);
        hipMemsetAsync(acc, 0, 4 * sizeof(float), stream);
        compact_kernel<<<(kN + 255) / 256, 256, 0, stream>>>(rmask, list, acc);
        convert_fp8_flat<<<kConvertBlocks, 256, 0, stream>>>(emb, tbl);
        row_loss_fp8<<<(kN + 3) / 4, 256, 0, stream>>>(emb, (const uchar*)tbl, nbr,
                                                       nbrm, neg, list, acc);
        finalize_kernel<<<1, 1, 0, stream>>>(acc, (float*)d_out);
    } else {
        hipMemsetAsync(acc, 0, 2 * sizeof(float), stream);
        row_loss_f32<<<kN / 4, 256, 0, stream>>>(emb, nbr, nbrm, neg, rmask, acc);
        finalize_f32<<<1, 1, 0, stream>>>(acc, (float*)d_out);
    }
}

// Round 12
// 303.540 us; speedup vs baseline: 1.1063x; 1.1063x over previous
//
#include <hip/hip_runtime.h>
#include <hip/hip_fp16.h>
#include <string.h>

namespace {
constexpr int kN = 50000;
constexpr int kD = 256;
constexpr int kPos = 32;
constexpr int kNeg = 20;
constexpr int kGathers = kPos + kNeg;  // 52
constexpr float kEps = 1e-15f;
constexpr int kSlots = kPos / 4 + kNeg / 4;  // 13 (legacy path)
constexpr int kCompactBlocks = (kN + 255) / 256;   // 196
constexpr int kConvertBlocks = kN * kD / 8 / 256;  // 6250
constexpr int kSliceD = 64;                        // dims per slice
constexpr int kNSlices = kD / kSliceD;             // 4
constexpr size_t kSliceBytes = (size_t)kN * kSliceD;  // 3.2 MB (fits 4MiB L2)

typedef float floatx2 __attribute__((ext_vector_type(2)));

#if __has_builtin(__builtin_amdgcn_cvt_pk_f32_fp8)
constexpr bool kHwCvtPk = true;
constexpr bool kHwCvt1 = false;
#elif __has_builtin(__builtin_amdgcn_cvt_f32_fp8)
constexpr bool kHwCvtPk = false;
constexpr bool kHwCvt1 = true;
#else
constexpr bool kHwCvtPk = false;
constexpr bool kHwCvt1 = false;
#endif
// software-decode fallback yields value*2^-8, so own must be pre-scaled by 256
constexpr float kOwnScale = (kHwCvtPk || kHwCvt1) ? 1.f : 256.f;

// ---------- fp8 e4m3fn encode ----------
__device__ __forceinline__ uint enc1(float x) {
    const __half hh = __float2half(x * 0.00390625f);  // x * 2^-8, HW RNE
    unsigned short t;
    memcpy(&t, &hh, 2);
    const uint s = ((uint)t >> 8) & 0x80u;
    uint mag = (uint)t & 0x7fffu;
    mag = mag + 0x3fu + ((mag >> 7) & 1u);  // RNE 10->3 bit mantissa
    uint u = mag >> 7;
    if (u > 0x7eu) u = 0x7eu;
    return s | u;
}

__device__ __forceinline__ uint enc4(const float4 a) {
#if __has_builtin(__builtin_amdgcn_cvt_pk_fp8_f32)
    int u = __builtin_amdgcn_cvt_pk_fp8_f32(a.x, a.y, 0, false);    // bytes 0,1
    u = __builtin_amdgcn_cvt_pk_fp8_f32(a.z, a.w, u, true);         // bytes 2,3
    return (uint)u;
#else
    return enc1(a.x) | (enc1(a.y) << 8) | (enc1(a.z) << 16) | (enc1(a.w) << 24);
#endif
}

__device__ __forceinline__ float dec_h(uint h) {
    __half hh;
    const unsigned short t = (unsigned short)h;
    memcpy(&hh, &t, 2);
    return __half2float(hh);
}

// Decode 4 packed e4m3 bytes, accumulate dot with o.x..o.w into d.
__device__ __forceinline__ void dq4f(uint u, const float4& o, float& d) {
#if __has_builtin(__builtin_amdgcn_cvt_pk_f32_fp8)
    const floatx2 lo = __builtin_amdgcn_cvt_pk_f32_fp8((int)u, false);  // bytes 0,1
    const floatx2 hi = __builtin_amdgcn_cvt_pk_f32_fp8((int)u, true);   // bytes 2,3
    d = fmaf(lo.x, o.x, d);
    d = fmaf(lo.y, o.y, d);
    d = fmaf(hi.x, o.z, d);
    d = fmaf(hi.y, o.w, d);
#elif __has_builtin(__builtin_amdgcn_cvt_f32_fp8)
    d = fmaf(__builtin_amdgcn_cvt_f32_fp8((int)u, 0), o.x, d);
    d = fmaf(__builtin_amdgcn_cvt_f32_fp8((int)u, 1), o.y, d);
    d = fmaf(__builtin_amdgcn_cvt_f32_fp8((int)u, 2), o.z, d);
    d = fmaf(__builtin_amdgcn_cvt_f32_fp8((int)u, 3), o.w, d);
#else
    const float v0 = dec_h(((u << 8) & 0x8000u) | ((u << 7) & 0x3f80u));
    const float v1 = dec_h((u & 0x8000u) | ((u >> 1) & 0x3f80u));
    const float v2 = dec_h(((u >> 8) & 0x8000u) | ((u >> 9) & 0x3f80u));
    const float v3 = dec_h(((u >> 16) & 0x8000u) | ((u >> 17) & 0x3f80u));
    d = fmaf(v0, o.x, d);
    d = fmaf(v1, o.y, d);
    d = fmaf(v2, o.z, d);
    d = fmaf(v3, o.w, d);
#endif
}

__device__ __forceinline__ void dq4(uint u, const float* o, float& d) {
    const float4 f = {o[0], o[1], o[2], o[3]};
    dq4f(u, f, d);
}

// ---------- fused prep: compaction + SLICED fp8 convert + out zeroing ----------
// Sliced layout: tbl[q*3.2MB + n*64 + j] (q = dim/64). One slice row = 64 B =
// exactly one cache line. Dest stores linear in tid; src reads coalesced.
__global__ __launch_bounds__(256) void prep_kernel(const float* __restrict__ emb,
                                                   uchar* __restrict__ tbl,
                                                   const int* __restrict__ rmask,
                                                   int* __restrict__ list,
                                                   float* __restrict__ acc,
                                                   float* __restrict__ out) {
    const int bid = blockIdx.x;
    if (bid < kCompactBlocks) {
        if (bid == 0 && threadIdx.x == 0) out[0] = 0.f;
        const int n = bid * 256 + threadIdx.x;
        if (n < kN && rmask[n]) {
            const int p = atomicAdd(reinterpret_cast<unsigned*>(&acc[2]), 1u);
            list[p] = n;
        }
    } else {
        const size_t a = ((size_t)(bid - kCompactBlocks) * 256 + threadIdx.x) * 8;
        const int q = (int)(a / kSliceBytes);
        const size_t r = a % kSliceBytes;
        const int n = (int)(r / kSliceD);
        const int j = (int)(r % kSliceD);  // 0,8,..,56
        const float* src = emb + (size_t)n * kD + q * kSliceD + j;
        const float4 f0 = reinterpret_cast<const float4*>(src)[0];
        const float4 f1 = reinterpret_cast<const float4*>(src)[1];
        uint2 o;
        o.x = enc4(f0);
        o.y = enc4(f1);
        *reinterpret_cast<uint2*>(tbl + a) = o;
    }
}

// ---------- Phase A: XCD-pinned partial dots, ATOMIC-FREE ----------
// Slice q handled only by blocks with bid%4==q -> HW round-robin puts them on
// XCDs q and q+4; slice (3.2 MB) stays L2-resident there. R11 lesson: the
// cross-XCD atomicAdd accumulation cost 152us (WRITE 62.7MB write-through);
// now each slice writes PRIVATE f16 partials dots[q][i][52] with plain
// stores; Phase B sums the 4 partials. One gather = one full 64B line
// consumed by a 16-lane group (100% line utilization).
// Materialization check: WRITE_SIZE ~21-25 MB, dur 30-45 us.
__global__ __launch_bounds__(256) void partial_dots(
    const float* __restrict__ emb,
    const uchar* __restrict__ tbl,
    const int* __restrict__ nbr,
    const int* __restrict__ neg,
    const int* __restrict__ list,
    const float* __restrict__ acc,
    __half* __restrict__ dots) {
    const int q = blockIdx.x & 3;    // slice id (XCD locality heuristic only)
    const int bs = blockIdx.x >> 2;  // block index within slice
    const int wave = threadIdx.x >> 6;
    const int lane = threadIdx.x & 63;
    const int g = lane >> 4;  // gather group 0..3
    const int t = lane & 15;  // dim-quad 0..15 within the 64-dim slice
    const int cnt_active = reinterpret_cast<const int*>(acc)[2];
    const uchar* slice = tbl + (size_t)q * kSliceBytes;
    const int wave_id = bs * 4 + wave;
    const int stride = (gridDim.x >> 2) * 4;  // waves per slice

    for (int i = wave_id; i < cnt_active; i += stride) {
        const int n = list[i];
        // own dims [q*64 + t*4, +4), exact fp32
        float4 own = reinterpret_cast<const float4*>(
            emb + (size_t)n * kD)[q * 16 + t];
        own.x *= kOwnScale;
        own.y *= kOwnScale;
        own.z *= kOwnScale;
        own.w *= kOwnScale;
        const int* nrow = nbr + (size_t)n * kPos;
        const int* grow = neg + (size_t)n * kNeg;
        __half* drow = dots + ((size_t)q * kN + (size_t)i) * kGathers;
#pragma unroll
        for (int k = 0; k < kGathers / 4; ++k) {  // 13
            const int gi = k * 4 + g;             // covers 0..51 exactly
            const int idx = gi < kPos ? nrow[gi] : grow[gi - kPos];
            const uint u = *reinterpret_cast<const uint*>(
                slice + (size_t)idx * kSliceD + t * 4);
            float d = 0.f;
            dq4f(u, own, d);
            d += __shfl_xor(d, 8);  // 16-lane group reduce (stays in group)
            d += __shfl_xor(d, 4);
            d += __shfl_xor(d, 2);
            d += __shfl_xor(d, 1);
            if (t == 0) drow[gi] = __float2half(d);  // plain store, no RMW
        }
    }
}

// ---------- Phase B: per-row loss from summed slice partials ----------
__global__ __launch_bounds__(256) void finish_loss(
    const int* __restrict__ nbrm,
    const int* __restrict__ list,
    const float* __restrict__ acc,
    const __half* __restrict__ dots,
    float* __restrict__ out) {
    __shared__ float s_num[4];
    const int wave = threadIdx.x >> 6;
    const int lane = threadIdx.x & 63;
    const int cnt_active = reinterpret_cast<const int*>(acc)[2];
    const int i = blockIdx.x * 4 + wave;
    float num = 0.f;

    if (i < cnt_active) {
        const int n = list[i];
        float pos_sum = 0.f, neg_sum = 0.f, cnt = 0.f;
        if (lane < kGathers) {
            float d = 0.f;
#pragma unroll
            for (int q = 0; q < kNSlices; ++q)
                d += __half2float(
                    dots[((size_t)q * kN + (size_t)i) * kGathers + lane]);
            const float sg = 1.f / (1.f + __expf(-d));
            if (lane < kPos) {
                const float m = (float)nbrm[(size_t)n * kPos + lane];
                pos_sum = -__logf(sg + kEps) * m;
                cnt = m;
            } else {
                neg_sum = -__logf(1.f - sg + kEps);
            }
        }
#pragma unroll
        for (int o = 32; o >= 1; o >>= 1) {
            pos_sum += __shfl_xor(pos_sum, o);
            neg_sum += __shfl_xor(neg_sum, o);
            cnt += __shfl_xor(cnt, o);
        }
        if (cnt > 0.f) num = pos_sum / cnt + neg_sum / (float)kNeg;
        // cnt==0 -> NaN row in reference -> replaced by 0 -> contributes 0
    }

    if (lane == 0) s_num[wave] = num;
    __syncthreads();
    if (threadIdx.x == 0) {
        const float v = s_num[0] + s_num[1] + s_num[2] + s_num[3];
        if (v != 0.f) atomicAdd(out, v / (float)cnt_active);
    }
}

// ---------- legacy flat-table fp8 path (mid-size ws; round-9 proven) ----------
__global__ __launch_bounds__(256) void convert_fp8_flat(const float* __restrict__ emb,
                                                        uint* __restrict__ tbl) {
    const size_t i = ((size_t)blockIdx.x * 256 + threadIdx.x) * 8;
    const float4* src = reinterpret_cast<const float4*>(emb + i);
    uint2 o;
    o.x = enc4(src[0]);
    o.y = enc4(src[1]);
    reinterpret_cast<uint2*>(tbl)[i / 8] = o;
}

__global__ __launch_bounds__(256) void compact_kernel(const int* __restrict__ rmask,
                                                      int* __restrict__ list,
                                                      float* __restrict__ acc) {
    const int n = blockIdx.x * 256 + threadIdx.x;
    if (n < kN && rmask[n]) {
        const int p = atomicAdd(reinterpret_cast<unsigned*>(&acc[2]), 1u);
        list[p] = n;
    }
}

__global__ __launch_bounds__(256) void row_loss_fp8(
    const float* __restrict__ emb,
    const uchar* __restrict__ tblb,
    const int* __restrict__ nbr,
    const int* __restrict__ nbrm,
    const int* __restrict__ neg,
    const int* __restrict__ list,
    float* __restrict__ acc) {
    __shared__ float s_num[4];
    const int wave = threadIdx.x >> 6;
    const int lane = threadIdx.x & 63;
    const int g = lane >> 4;
    const int t = lane & 15;
    const uint lane_off = (uint)t * 16u;

    const int cnt_active = reinterpret_cast<const int*>(acc)[2];
    const int i = blockIdx.x * 4 + wave;
    float num = 0.f;

    if (i < cnt_active) {
        const int n = list[i];
        const float4* erow = reinterpret_cast<const float4*>(emb + (size_t)n * kD);
        float own[16];
#pragma unroll
        for (int j = 0; j < 4; ++j) {
            const float4 f = erow[4 * t + j];
            own[4 * j + 0] = f.x * kOwnScale;
            own[4 * j + 1] = f.y * kOwnScale;
            own[4 * j + 2] = f.z * kOwnScale;
            own[4 * j + 3] = f.w * kOwnScale;
        }
        const int* nrow = nbr + (size_t)n * kPos;
        const int* mrow = nbrm + (size_t)n * kPos;
        const int* grow = neg + (size_t)n * kNeg;
        uint off[kSlots];
        float w[kPos / 4];
        float cnt = 0.f;
#pragma unroll
        for (int s = 0; s < kPos / 4; ++s) {
            off[s] = ((uint)nrow[s * 4 + g] << 8) + lane_off;
            const float mf = (float)mrow[s * 4 + g];
            w[s] = mf;
            cnt += mf;
        }
#pragma unroll
        for (int s = 0; s < kNeg / 4; ++s)
            off[kPos / 4 + s] = ((uint)grow[s * 4 + g] << 8) + lane_off;

        float pos_sum = 0.f, neg_sum = 0.f;
        uint4 u = *reinterpret_cast<const uint4*>(tblb + off[0]);
#pragma unroll
        for (int s = 0; s < kSlots; ++s) {
            const uint4 uc = u;
            if (s + 1 < kSlots)
                u = *reinterpret_cast<const uint4*>(tblb + off[s + 1]);
            float d = 0.f;
            dq4(uc.x, own + 0, d);
            dq4(uc.y, own + 4, d);
            dq4(uc.z, own + 8, d);
            dq4(uc.w, own + 12, d);
            d += __shfl_xor(d, 8);
            d += __shfl_xor(d, 4);
            d += __shfl_xor(d, 2);
            d += __shfl_xor(d, 1);
            const float sg = 1.f / (1.f + __expf(-d));
            if (s < kPos / 4) {
                pos_sum += -__logf(sg + kEps) * w[s];
            } else {
                neg_sum += -__logf(1.f - sg + kEps);
            }
        }
        pos_sum += __shfl_xor(pos_sum, 16);
        pos_sum += __shfl_xor(pos_sum, 32);
        neg_sum += __shfl_xor(neg_sum, 16);
        neg_sum += __shfl_xor(neg_sum, 32);
        cnt += __shfl_xor(cnt, 16);
        cnt += __shfl_xor(cnt, 32);
        if (cnt > 0.f) num = pos_sum / cnt + neg_sum / (float)kNeg;
    }

    if (lane == 0) s_num[wave] = num;
    __syncthreads();
    if (threadIdx.x == 0) {
        const float v = s_num[0] + s_num[1] + s_num[2] + s_num[3];
        if (v != 0.f) atomicAdd(&acc[0], v);
    }
}

__global__ void finalize_kernel(const float* __restrict__ acc, float* __restrict__ out) {
    out[0] = acc[0] / (float)reinterpret_cast<const int*>(acc)[2];
}

// ---------- fp32 direct fallback (tiny ws; UNCHANGED) ----------
__global__ __launch_bounds__(256) void row_loss_f32(
    const float* __restrict__ emb,
    const int* __restrict__ nbr,
    const int* __restrict__ nbrm,
    const int* __restrict__ neg,
    const int* __restrict__ rmask,
    float* __restrict__ acc) {
    __shared__ float s_num[4];
    __shared__ float s_den[4];
    const int wave = threadIdx.x >> 6;
    const int lane = threadIdx.x & 63;
    const int n = blockIdx.x * 4 + wave;
    const int g = lane >> 4;
    const int t = lane & 15;

    const float4* erow = reinterpret_cast<const float4*>(emb + (size_t)n * kD);
    float4 own4[4];
#pragma unroll
    for (int j = 0; j < 4; ++j) own4[j] = erow[j * 16 + t];

    const int* nrow = nbr + (size_t)n * kPos;
    const int* mrow = nbrm + (size_t)n * kPos;
    const int* grow = neg + (size_t)n * kNeg;

    float pos_sum = 0.f, neg_sum = 0.f, cnt = 0.f;
#pragma unroll
    for (int it = 0; it < kPos / 4; ++it) {
        const int idx = nrow[it * 4 + g];
        const float mf = (float)mrow[it * 4 + g];
        cnt += mf;
        const float4* brow = reinterpret_cast<const float4*>(emb + (size_t)idx * kD);
        float d = 0.f;
#pragma unroll
        for (int j = 0; j < 4; ++j) {
            const float4 b = brow[j * 16 + t];
            const float4 a = own4[j];
            d += a.x * b.x + a.y * b.y + a.z * b.z + a.w * b.w;
        }
        d += __shfl_xor(d, 8);
        d += __shfl_xor(d, 4);
        d += __shfl_xor(d, 2);
        d += __shfl_xor(d, 1);
        const float s = 1.f / (1.f + __expf(-d));
        pos_sum += -__logf(s + kEps) * mf;
    }
#pragma unroll
    for (int it = 0; it < kNeg / 4; ++it) {
        const int idx = grow[it * 4 + g];
        const float4* brow = reinterpret_cast<const float4*>(emb + (size_t)idx * kD);
        float d = 0.f;
#pragma unroll
        for (int j = 0; j < 4; ++j) {
            const float4 b = brow[j * 16 + t];
            const float4 a = own4[j];
            d += a.x * b.x + a.y * b.y + a.z * b.z + a.w * b.w;
        }
        d += __shfl_xor(d, 8);
        d += __shfl_xor(d, 4);
        d += __shfl_xor(d, 2);
        d += __shfl_xor(d, 1);
        const float s = 1.f / (1.f + __expf(-d));
        neg_sum += -__logf(1.f - s + kEps);
    }

    pos_sum += __shfl_xor(pos_sum, 16);
    pos_sum += __shfl_xor(pos_sum, 32);
    neg_sum += __shfl_xor(neg_sum, 16);
    neg_sum += __shfl_xor(neg_sum, 32);
    cnt += __shfl_xor(cnt, 16);
    cnt += __shfl_xor(cnt, 32);

    float num = 0.f;
    if (cnt > 0.f) num = pos_sum / cnt + neg_sum / (float)kNeg;
    const float rmf = (float)rmask[n];

    if (lane == 0) {
        s_num[wave] = num * rmf;
        s_den[wave] = rmf;
    }
    __syncthreads();
    if (threadIdx.x == 0) {
        atomicAdd(&acc[0], s_num[0] + s_num[1] + s_num[2] + s_num[3]);
        atomicAdd(&acc[1], s_den[0] + s_den[1] + s_den[2] + s_den[3]);
    }
}

__global__ void finalize_f32(const float* __restrict__ acc, float* __restrict__ out) {
    out[0] = acc[0] / acc[1];
}
}  // namespace

extern "C" void kernel_launch(void* const* d_in, const int* in_sizes, int n_in,
                              void* d_out, int out_size, void* d_ws, size_t ws_size,
                              hipStream_t stream) {
    const float* emb = (const float*)d_in[0];
    const int* nbr = (const int*)d_in[1];
    const int* nbrm = (const int*)d_in[2];
    const int* neg = (const int*)d_in[3];
    const int* rmask = (const int*)d_in[4];
    float* acc = (float*)d_ws;  // [0]=num, [1]=den, [2]=active count

    const size_t tbl_bytes = (size_t)kN * kD;            // 12.8 MB
    const size_t list_bytes = (size_t)kN * sizeof(int);  // 0.2 MB
    const size_t dots_bytes =
        (size_t)kNSlices * kN * kGathers * sizeof(__half);  // 20.8 MB

    if (ws_size >= 256 + dots_bytes + tbl_bytes + list_bytes) {
        // ---- XCD-sliced two-phase path (atomic-free partials) ----
        __half* dots = (__half*)((char*)d_ws + 256);
        uchar* tbl = (uchar*)d_ws + 256 + dots_bytes;
        int* list = (int*)((char*)d_ws + 256 + dots_bytes + tbl_bytes);
        hipMemsetAsync(acc, 0, 4 * sizeof(float), stream);
        prep_kernel<<<kCompactBlocks + kConvertBlocks, 256, 0, stream>>>(
            emb, tbl, rmask, list, acc, (float*)d_out);
        partial_dots<<<2048, 256, 0, stream>>>(emb, tbl, nbr, neg, list, acc, dots);
        finish_loss<<<(kN + 3) / 4, 256, 0, stream>>>(nbrm, list, acc, dots,
                                                      (float*)d_out);
    } else if (ws_size >= 256 + tbl_bytes + list_bytes) {
        // ---- legacy flat-table fp8 path (round-9 proven, ~196 us e2e) ----
        uint* tbl = (uint*)((char*)d_ws + 256);
        int* list = (int*)((char*)d_ws + 256 + tbl_bytes);
        hipMemsetAsync(acc, 0, 4 * sizeof(float), stream);
        compact_kernel<<<(kN + 255) / 256, 256, 0, stream>>>(rmask, list, acc);
        convert_fp8_flat<<<kConvertBlocks, 256, 0, stream>>>(emb, tbl);
        row_loss_fp8<<<(kN + 3) / 4, 256, 0, stream>>>(emb, (const uchar*)tbl, nbr,
                                                       nbrm, neg, list, acc);
        finalize_kernel<<<1, 1, 0, stream>>>(acc, (float*)d_out);
    } else {
        hipMemsetAsync(acc, 0, 2 * sizeof(float), stream);
        row_loss_f32<<<kN / 4, 256, 0, stream>>>(emb, nbr, nbrm, neg, rmask, acc);
        finalize_f32<<<1, 1, 0, stream>>>(acc, (float*)d_out);
    }
}

// Round 13
// 242.642 us; speedup vs baseline: 1.3839x; 1.2510x over previous
//
#include <hip/hip_runtime.h>
#include <hip/hip_fp16.h>
#include <string.h>

namespace {
constexpr int kN = 50000;
constexpr int kD = 256;
constexpr int kPos = 32;
constexpr int kNeg = 20;
constexpr int kGathers = kPos + kNeg;  // 52
constexpr float kEps = 1e-15f;
constexpr int kSlots = kPos / 4 + kNeg / 4;  // 13 (legacy path)
constexpr int kCompactBlocks = (kN + 255) / 256;   // 196
constexpr int kConvertBlocks = kN * kD / 8 / 256;  // 6250
constexpr int kSliceD = 64;                        // dims per slice
constexpr int kNSlices = kD / kSliceD;             // 4
constexpr size_t kSliceBytes = (size_t)kN * kSliceD;  // 3.2 MB (fits 4MiB L2)

typedef float floatx2 __attribute__((ext_vector_type(2)));

#if __has_builtin(__builtin_amdgcn_cvt_pk_f32_fp8)
constexpr bool kHwCvtPk = true;
constexpr bool kHwCvt1 = false;
#elif __has_builtin(__builtin_amdgcn_cvt_f32_fp8)
constexpr bool kHwCvtPk = false;
constexpr bool kHwCvt1 = true;
#else
constexpr bool kHwCvtPk = false;
constexpr bool kHwCvt1 = false;
#endif
// software-decode fallback yields value*2^-8, so own must be pre-scaled by 256
constexpr float kOwnScale = (kHwCvtPk || kHwCvt1) ? 1.f : 256.f;

// ---------- fp8 e4m3fn encode ----------
__device__ __forceinline__ uint enc1(float x) {
    const __half hh = __float2half(x * 0.00390625f);  // x * 2^-8, HW RNE
    unsigned short t;
    memcpy(&t, &hh, 2);
    const uint s = ((uint)t >> 8) & 0x80u;
    uint mag = (uint)t & 0x7fffu;
    mag = mag + 0x3fu + ((mag >> 7) & 1u);  // RNE 10->3 bit mantissa
    uint u = mag >> 7;
    if (u > 0x7eu) u = 0x7eu;
    return s | u;
}

__device__ __forceinline__ uint enc4(const float4 a) {
#if __has_builtin(__builtin_amdgcn_cvt_pk_fp8_f32)
    int u = __builtin_amdgcn_cvt_pk_fp8_f32(a.x, a.y, 0, false);    // bytes 0,1
    u = __builtin_amdgcn_cvt_pk_fp8_f32(a.z, a.w, u, true);         // bytes 2,3
    return (uint)u;
#else
    return enc1(a.x) | (enc1(a.y) << 8) | (enc1(a.z) << 16) | (enc1(a.w) << 24);
#endif
}

__device__ __forceinline__ float dec_h(uint h) {
    __half hh;
    const unsigned short t = (unsigned short)h;
    memcpy(&hh, &t, 2);
    return __half2float(hh);
}

// Decode 4 packed e4m3 bytes, accumulate dot with o[0..3] into d.
__device__ __forceinline__ void dq4(uint u, const float* o, float& d) {
#if __has_builtin(__builtin_amdgcn_cvt_pk_f32_fp8)
    const floatx2 lo = __builtin_amdgcn_cvt_pk_f32_fp8((int)u, false);  // bytes 0,1
    const floatx2 hi = __builtin_amdgcn_cvt_pk_f32_fp8((int)u, true);   // bytes 2,3
    d = fmaf(lo.x, o[0], d);
    d = fmaf(lo.y, o[1], d);
    d = fmaf(hi.x, o[2], d);
    d = fmaf(hi.y, o[3], d);
#elif __has_builtin(__builtin_amdgcn_cvt_f32_fp8)
    d = fmaf(__builtin_amdgcn_cvt_f32_fp8((int)u, 0), o[0], d);
    d = fmaf(__builtin_amdgcn_cvt_f32_fp8((int)u, 1), o[1], d);
    d = fmaf(__builtin_amdgcn_cvt_f32_fp8((int)u, 2), o[2], d);
    d = fmaf(__builtin_amdgcn_cvt_f32_fp8((int)u, 3), o[3], d);
#else
    const float v0 = dec_h(((u << 8) & 0x8000u) | ((u << 7) & 0x3f80u));
    const float v1 = dec_h((u & 0x8000u) | ((u >> 1) & 0x3f80u));
    const float v2 = dec_h(((u >> 8) & 0x8000u) | ((u >> 9) & 0x3f80u));
    const float v3 = dec_h(((u >> 16) & 0x8000u) | ((u >> 17) & 0x3f80u));
    d = fmaf(v0, o[0], d);
    d = fmaf(v1, o[1], d);
    d = fmaf(v2, o[2], d);
    d = fmaf(v3, o[3], d);
#endif
}

// ---------- fused prep: compaction + SLICED fp8 convert + out zeroing ----------
// Sliced layout: tbl[q*3.2MB + n*64 + j] (q = dim/64). One slice row = 64 B =
// exactly one cache line. Dest stores linear in tid; src reads coalesced.
__global__ __launch_bounds__(256) void prep_kernel(const float* __restrict__ emb,
                                                   uchar* __restrict__ tbl,
                                                   const int* __restrict__ rmask,
                                                   int* __restrict__ list,
                                                   float* __restrict__ acc,
                                                   float* __restrict__ out) {
    const int bid = blockIdx.x;
    if (bid < kCompactBlocks) {
        if (bid == 0 && threadIdx.x == 0) out[0] = 0.f;
        const int n = bid * 256 + threadIdx.x;
        if (n < kN && rmask[n]) {
            const int p = atomicAdd(reinterpret_cast<unsigned*>(&acc[2]), 1u);
            list[p] = n;
        }
    } else {
        const size_t a = ((size_t)(bid - kCompactBlocks) * 256 + threadIdx.x) * 8;
        const int q = (int)(a / kSliceBytes);
        const size_t r = a % kSliceBytes;
        const int n = (int)(r / kSliceD);
        const int j = (int)(r % kSliceD);  // 0,8,..,56
        const float* src = emb + (size_t)n * kD + q * kSliceD + j;
        const float4 f0 = reinterpret_cast<const float4*>(src)[0];
        const float4 f1 = reinterpret_cast<const float4*>(src)[1];
        uint2 o;
        o.x = enc4(f0);
        o.y = enc4(f1);
        *reinterpret_cast<uint2*>(tbl + a) = o;
    }
}

// ---------- Phase A: XCD-pinned partial dots — round-1 codegen shape ----------
// One wave per (row, slice): grid = 4 slices x ceil(kN/4) blocks; bid&3 = slice
// (HW round-robin -> XCDs {q,q+4}; 3.2MB slice L2-resident there). Wave = 16
// groups x 4 lanes; group grp handles gather slot gi = it*16+grp (4 iters
// cover 52); lane sub loads uint4 at idx*64+sub*16 -> a 4-lane group consumes
// exactly one 64B line; a wave instruction moves 1KB/16 lines (full line
// utilization, same as the proven round-1 gather). 2 shfls per slot (4-lane
// reduce); sub==0 lanes store 16 consecutive f16 partials (32B contiguous).
// R12 lesson: grid-stride + per-iter dword gathers got sunk to VGPR=16 and
// serialized. This is round-1's register/control shape (preloaded offsets,
// prefetched gathers) which reliably compiles to ~56 VGPR with pipelining.
// Materialization check: VGPR 45-60 (16 again = experiment void).
__global__ __launch_bounds__(256) void partial_dots(
    const float* __restrict__ emb,
    const uchar* __restrict__ tbl,
    const int* __restrict__ nbr,
    const int* __restrict__ neg,
    const int* __restrict__ list,
    const float* __restrict__ acc,
    __half* __restrict__ dots) {
    const int q = blockIdx.x & 3;    // slice id (XCD locality heuristic only)
    const int bs = blockIdx.x >> 2;  // block index within slice
    const int wave = threadIdx.x >> 6;
    const int lane = threadIdx.x & 63;
    const int grp = lane >> 2;  // gather group 0..15
    const int sub = lane & 3;   // 16B chunk within the 64B slice row
    const int cnt_active = reinterpret_cast<const int*>(acc)[2];
    const uchar* slice = tbl + (size_t)q * kSliceBytes;
    const int i = bs * 4 + wave;

    if (i < cnt_active) {  // wave-uniform
        const int n = list[i];

        // own dims for this lane: [q*64 + sub*16, +16), exact fp32
        const float4* erow =
            reinterpret_cast<const float4*>(emb + (size_t)n * kD + q * kSliceD);
        float own[16];
#pragma unroll
        for (int j = 0; j < 4; ++j) {
            const float4 f = erow[sub * 4 + j];
            own[4 * j + 0] = f.x * kOwnScale;
            own[4 * j + 1] = f.y * kOwnScale;
            own[4 * j + 2] = f.z * kOwnScale;
            own[4 * j + 3] = f.w * kOwnScale;
        }

        const int* nrow = nbr + (size_t)n * kPos;
        const int* grow = neg + (size_t)n * kNeg;

        // preload this group's 4 slot offsets (gi = it*16 + grp)
        uint off[4];
#pragma unroll
        for (int it = 0; it < 4; ++it) {
            const int gi = it * 16 + grp;
            const int gic = gi < kGathers ? gi : 0;  // clamp pad slots
            const int idx = gic < kPos ? nrow[gic] : grow[gic - kPos];
            off[it] = ((uint)idx << 6) + (uint)sub * 16u;
        }

        __half* drow = dots + ((size_t)q * kN + (size_t)i) * kGathers;

        // 1-deep prefetch over the 4 slots (round-1 idiom)
        uint4 u = *reinterpret_cast<const uint4*>(slice + off[0]);
#pragma unroll
        for (int it = 0; it < 4; ++it) {
            const uint4 uc = u;
            if (it + 1 < 4) u = *reinterpret_cast<const uint4*>(slice + off[it + 1]);
            float d = 0.f;
            dq4(uc.x, own + 0, d);
            dq4(uc.y, own + 4, d);
            dq4(uc.z, own + 8, d);
            dq4(uc.w, own + 12, d);
            d += __shfl_xor(d, 1);  // 4-lane group reduce
            d += __shfl_xor(d, 2);
            const int gi = it * 16 + grp;
            if (sub == 0 && gi < kGathers) drow[gi] = __float2half(d);
        }
    }
}

// ---------- Phase B: per-row loss from summed slice partials ----------
__global__ __launch_bounds__(256) void finish_loss(
    const int* __restrict__ nbrm,
    const int* __restrict__ list,
    const float* __restrict__ acc,
    const __half* __restrict__ dots,
    float* __restrict__ out) {
    __shared__ float s_num[4];
    const int wave = threadIdx.x >> 6;
    const int lane = threadIdx.x & 63;
    const int cnt_active = reinterpret_cast<const int*>(acc)[2];
    const int i = blockIdx.x * 4 + wave;
    float num = 0.f;

    if (i < cnt_active) {
        const int n = list[i];
        float pos_sum = 0.f, neg_sum = 0.f, cnt = 0.f;
        if (lane < kGathers) {
            float d = 0.f;
#pragma unroll
            for (int q = 0; q < kNSlices; ++q)
                d += __half2float(
                    dots[((size_t)q * kN + (size_t)i) * kGathers + lane]);
            const float sg = 1.f / (1.f + __expf(-d));
            if (lane < kPos) {
                const float m = (float)nbrm[(size_t)n * kPos + lane];
                pos_sum = -__logf(sg + kEps) * m;
                cnt = m;
            } else {
                neg_sum = -__logf(1.f - sg + kEps);
            }
        }
#pragma unroll
        for (int o = 32; o >= 1; o >>= 1) {
            pos_sum += __shfl_xor(pos_sum, o);
            neg_sum += __shfl_xor(neg_sum, o);
            cnt += __shfl_xor(cnt, o);
        }
        if (cnt > 0.f) num = pos_sum / cnt + neg_sum / (float)kNeg;
        // cnt==0 -> NaN row in reference -> replaced by 0 -> contributes 0
    }

    if (lane == 0) s_num[wave] = num;
    __syncthreads();
    if (threadIdx.x == 0) {
        const float v = s_num[0] + s_num[1] + s_num[2] + s_num[3];
        if (v != 0.f) atomicAdd(out, v / (float)cnt_active);
    }
}

// ---------- legacy flat-table fp8 path (mid-size ws; round-9 proven) ----------
__global__ __launch_bounds__(256) void convert_fp8_flat(const float* __restrict__ emb,
                                                        uint* __restrict__ tbl) {
    const size_t i = ((size_t)blockIdx.x * 256 + threadIdx.x) * 8;
    const float4* src = reinterpret_cast<const float4*>(emb + i);
    uint2 o;
    o.x = enc4(src[0]);
    o.y = enc4(src[1]);
    reinterpret_cast<uint2*>(tbl)[i / 8] = o;
}

__global__ __launch_bounds__(256) void compact_kernel(const int* __restrict__ rmask,
                                                      int* __restrict__ list,
                                                      float* __restrict__ acc) {
    const int n = blockIdx.x * 256 + threadIdx.x;
    if (n < kN && rmask[n]) {
        const int p = atomicAdd(reinterpret_cast<unsigned*>(&acc[2]), 1u);
        list[p] = n;
    }
}

__global__ __launch_bounds__(256) void row_loss_fp8(
    const float* __restrict__ emb,
    const uchar* __restrict__ tblb,
    const int* __restrict__ nbr,
    const int* __restrict__ nbrm,
    const int* __restrict__ neg,
    const int* __restrict__ list,
    float* __restrict__ acc) {
    __shared__ float s_num[4];
    const int wave = threadIdx.x >> 6;
    const int lane = threadIdx.x & 63;
    const int g = lane >> 4;
    const int t = lane & 15;
    const uint lane_off = (uint)t * 16u;

    const int cnt_active = reinterpret_cast<const int*>(acc)[2];
    const int i = blockIdx.x * 4 + wave;
    float num = 0.f;

    if (i < cnt_active) {
        const int n = list[i];
        const float4* erow = reinterpret_cast<const float4*>(emb + (size_t)n * kD);
        float own[16];
#pragma unroll
        for (int j = 0; j < 4; ++j) {
            const float4 f = erow[4 * t + j];
            own[4 * j + 0] = f.x * kOwnScale;
            own[4 * j + 1] = f.y * kOwnScale;
            own[4 * j + 2] = f.z * kOwnScale;
            own[4 * j + 3] = f.w * kOwnScale;
        }
        const int* nrow = nbr + (size_t)n * kPos;
        const int* mrow = nbrm + (size_t)n * kPos;
        const int* grow = neg + (size_t)n * kNeg;
        uint off[kSlots];
        float w[kPos / 4];
        float cnt = 0.f;
#pragma unroll
        for (int s = 0; s < kPos / 4; ++s) {
            off[s] = ((uint)nrow[s * 4 + g] << 8) + lane_off;
            const float mf = (float)mrow[s * 4 + g];
            w[s] = mf;
            cnt += mf;
        }
#pragma unroll
        for (int s = 0; s < kNeg / 4; ++s)
            off[kPos / 4 + s] = ((uint)grow[s * 4 + g] << 8) + lane_off;

        float pos_sum = 0.f, neg_sum = 0.f;
        uint4 u = *reinterpret_cast<const uint4*>(tblb + off[0]);
#pragma unroll
        for (int s = 0; s < kSlots; ++s) {
            const uint4 uc = u;
            if (s + 1 < kSlots)
                u = *reinterpret_cast<const uint4*>(tblb + off[s + 1]);
            float d = 0.f;
            dq4(uc.x, own + 0, d);
            dq4(uc.y, own + 4, d);
            dq4(uc.z, own + 8, d);
            dq4(uc.w, own + 12, d);
            d += __shfl_xor(d, 8);
            d += __shfl_xor(d, 4);
            d += __shfl_xor(d, 2);
            d += __shfl_xor(d, 1);
            const float sg = 1.f / (1.f + __expf(-d));
            if (s < kPos / 4) {
                pos_sum += -__logf(sg + kEps) * w[s];
            } else {
                neg_sum += -__logf(1.f - sg + kEps);
            }
        }
        pos_sum += __shfl_xor(pos_sum, 16);
        pos_sum += __shfl_xor(pos_sum, 32);
        neg_sum += __shfl_xor(neg_sum, 16);
        neg_sum += __shfl_xor(neg_sum, 32);
        cnt += __shfl_xor(cnt, 16);
        cnt += __shfl_xor(cnt, 32);
        if (cnt > 0.f) num = pos_sum / cnt + neg_sum / (float)kNeg;
    }

    if (lane == 0) s_num[wave] = num;
    __syncthreads();
    if (threadIdx.x == 0) {
        const float v = s_num[0] + s_num[1] + s_num[2] + s_num[3];
        if (v != 0.f) atomicAdd(&acc[0], v);
    }
}

__global__ void finalize_kernel(const float* __restrict__ acc, float* __restrict__ out) {
    out[0] = acc[0] / (float)reinterpret_cast<const int*>(acc)[2];
}

// ---------- fp32 direct fallback (tiny ws; UNCHANGED) ----------
__global__ __launch_bounds__(256) void row_loss_f32(
    const float* __restrict__ emb,
    const int* __restrict__ nbr,
    const int* __restrict__ nbrm,
    const int* __restrict__ neg,
    const int* __restrict__ rmask,
    float* __restrict__ acc) {
    __shared__ float s_num[4];
    __shared__ float s_den[4];
    const int wave = threadIdx.x >> 6;
    const int lane = threadIdx.x & 63;
    const int n = blockIdx.x * 4 + wave;
    const int g = lane >> 4;
    const int t = lane & 15;

    const float4* erow = reinterpret_cast<const float4*>(emb + (size_t)n * kD);
    float4 own4[4];
#pragma unroll
    for (int j = 0; j < 4; ++j) own4[j] = erow[j * 16 + t];

    const int* nrow = nbr + (size_t)n * kPos;
    const int* mrow = nbrm + (size_t)n * kPos;
    const int* grow = neg + (size_t)n * kNeg;

    float pos_sum = 0.f, neg_sum = 0.f, cnt = 0.f;
#pragma unroll
    for (int it = 0; it < kPos / 4; ++it) {
        const int idx = nrow[it * 4 + g];
        const float mf = (float)mrow[it * 4 + g];
        cnt += mf;
        const float4* brow = reinterpret_cast<const float4*>(emb + (size_t)idx * kD);
        float d = 0.f;
#pragma unroll
        for (int j = 0; j < 4; ++j) {
            const float4 b = brow[j * 16 + t];
            const float4 a = own4[j];
            d += a.x * b.x + a.y * b.y + a.z * b.z + a.w * b.w;
        }
        d += __shfl_xor(d, 8);
        d += __shfl_xor(d, 4);
        d += __shfl_xor(d, 2);
        d += __shfl_xor(d, 1);
        const float s = 1.f / (1.f + __expf(-d));
        pos_sum += -__logf(s + kEps) * mf;
    }
#pragma unroll
    for (int it = 0; it < kNeg / 4; ++it) {
        const int idx = grow[it * 4 + g];
        const float4* brow = reinterpret_cast<const float4*>(emb + (size_t)idx * kD);
        float d = 0.f;
#pragma unroll
        for (int j = 0; j < 4; ++j) {
            const float4 b = brow[j * 16 + t];
            const float4 a = own4[j];
            d += a.x * b.x + a.y * b.y + a.z * b.z + a.w * b.w;
        }
        d += __shfl_xor(d, 8);
        d += __shfl_xor(d, 4);
        d += __shfl_xor(d, 2);
        d += __shfl_xor(d, 1);
        const float s = 1.f / (1.f + __expf(-d));
        neg_sum += -__logf(1.f - s + kEps);
    }

    pos_sum += __shfl_xor(pos_sum, 16);
    pos_sum += __shfl_xor(pos_sum, 32);
    neg_sum += __shfl_xor(neg_sum, 16);
    neg_sum += __shfl_xor(neg_sum, 32);
    cnt += __shfl_xor(cnt, 16);
    cnt += __shfl_xor(cnt, 32);

    float num = 0.f;
    if (cnt > 0.f) num = pos_sum / cnt + neg_sum / (float)kNeg;
    const float rmf = (float)rmask[n];

    if (lane == 0) {
        s_num[wave] = num * rmf;
        s_den[wave] = rmf;
    }
    __syncthreads();
    if (threadIdx.x == 0) {
        atomicAdd(&acc[0], s_num[0] + s_num[1] + s_num[2] + s_num[3]);
        atomicAdd(&acc[1], s_den[0] + s_den[1] + s_den[2] + s_den[3]);
    }
}

__global__ void finalize_f32(const float* __restrict__ acc, float* __restrict__ out) {
    out[0] = acc[0] / acc[1];
}
}  // namespace

extern "C" void kernel_launch(void* const* d_in, const int* in_sizes, int n_in,
                              void* d_out, int out_size, void* d_ws, size_t ws_size,
                              hipStream_t stream) {
    const float* emb = (const float*)d_in[0];
    const int* nbr = (const int*)d_in[1];
    const int* nbrm = (const int*)d_in[2];
    const int* neg = (const int*)d_in[3];
    const int* rmask = (const int*)d_in[4];
    float* acc = (float*)d_ws;  // [0]=num, [1]=den, [2]=active count

    const size_t tbl_bytes = (size_t)kN * kD;            // 12.8 MB
    const size_t list_bytes = (size_t)kN * sizeof(int);  // 0.2 MB
    const size_t dots_bytes =
        (size_t)kNSlices * kN * kGathers * sizeof(__half);  // 20.8 MB

    if (ws_size >= 256 + dots_bytes + tbl_bytes + list_bytes) {
        // ---- XCD-sliced two-phase path (atomic-free, round-1-shaped) ----
        __half* dots = (__half*)((char*)d_ws + 256);
        uchar* tbl = (uchar*)d_ws + 256 + dots_bytes;
        int* list = (int*)((char*)d_ws + 256 + dots_bytes + tbl_bytes);
        hipMemsetAsync(acc, 0, 4 * sizeof(float), stream);
        prep_kernel<<<kCompactBlocks + kConvertBlocks, 256, 0, stream>>>(
            emb, tbl, rmask, list, acc, (float*)d_out);
        partial_dots<<<kNSlices * ((kN + 3) / 4), 256, 0, stream>>>(
            emb, tbl, nbr, neg, list, acc, dots);
        finish_loss<<<(kN + 3) / 4, 256, 0, stream>>>(nbrm, list, acc, dots,
                                                      (float*)d_out);
    } else if (ws_size >= 256 + tbl_bytes + list_bytes) {
        // ---- legacy flat-table fp8 path (round-9 proven, ~196 us e2e) ----
        uint* tbl = (uint*)((char*)d_ws + 256);
        int* list = (int*)((char*)d_ws + 256 + tbl_bytes);
        hipMemsetAsync(acc, 0, 4 * sizeof(float), stream);
        compact_kernel<<<(kN + 255) / 256, 256, 0, stream>>>(rmask, list, acc);
        convert_fp8_flat<<<kConvertBlocks, 256, 0, stream>>>(emb, tbl);
        row_loss_fp8<<<(kN + 3) / 4, 256, 0, stream>>>(emb, (const uchar*)tbl, nbr,
                                                       nbrm, neg, list, acc);
        finalize_kernel<<<1, 1, 0, stream>>>(acc, (float*)d_out);
    } else {
        hipMemsetAsync(acc, 0, 2 * sizeof(float), stream);
        row_loss_f32<<<kN / 4, 256, 0, stream>>>(emb, nbr, nbrm, neg, rmask, acc);
        finalize_f32<<<1, 1, 0, stream>>>(acc, (float*)d_out);
    }
}

// Round 14
// 171.789 us; speedup vs baseline: 1.9547x; 1.4124x over previous
//
#include <hip/hip_runtime.h>
#include <hip/hip_fp16.h>
#include <string.h>

namespace {
constexpr int kN = 50000;
constexpr int kD = 256;
constexpr int kPos = 32;
constexpr int kNeg = 20;
constexpr float kEps = 1e-15f;
constexpr int kSlots = kPos / 4 + kNeg / 4;  // 13 per 16-lane group
constexpr int kCompactBlocks = (kN + 255) / 256;   // 196
constexpr int kConvertBlocks = kN * kD / 8 / 256;  // 6250
constexpr int kRowBlocks = (kN + 3) / 4;           // 12500

typedef float floatx2 __attribute__((ext_vector_type(2)));

#if __has_builtin(__builtin_amdgcn_cvt_pk_f32_fp8)
constexpr bool kHwCvtPk = true;
constexpr bool kHwCvt1 = false;
#elif __has_builtin(__builtin_amdgcn_cvt_f32_fp8)
constexpr bool kHwCvtPk = false;
constexpr bool kHwCvt1 = true;
#else
constexpr bool kHwCvtPk = false;
constexpr bool kHwCvt1 = false;
#endif
// software-decode fallback yields value*2^-8, so own must be pre-scaled by 256
constexpr float kOwnScale = (kHwCvtPk || kHwCvt1) ? 1.f : 256.f;

// ---------- fp8 e4m3fn encode ----------
__device__ __forceinline__ uint enc1(float x) {
    const __half hh = __float2half(x * 0.00390625f);  // x * 2^-8, HW RNE
    unsigned short t;
    memcpy(&t, &hh, 2);
    const uint s = ((uint)t >> 8) & 0x80u;
    uint mag = (uint)t & 0x7fffu;
    mag = mag + 0x3fu + ((mag >> 7) & 1u);  // RNE 10->3 bit mantissa
    uint u = mag >> 7;
    if (u > 0x7eu) u = 0x7eu;
    return s | u;
}

__device__ __forceinline__ uint enc4(const float4 a) {
#if __has_builtin(__builtin_amdgcn_cvt_pk_fp8_f32)
    int u = __builtin_amdgcn_cvt_pk_fp8_f32(a.x, a.y, 0, false);    // bytes 0,1
    u = __builtin_amdgcn_cvt_pk_fp8_f32(a.z, a.w, u, true);         // bytes 2,3
    return (uint)u;
#else
    return enc1(a.x) | (enc1(a.y) << 8) | (enc1(a.z) << 16) | (enc1(a.w) << 24);
#endif
}

__device__ __forceinline__ float dec_h(uint h) {
    __half hh;
    const unsigned short t = (unsigned short)h;
    memcpy(&hh, &t, 2);
    return __half2float(hh);
}

// Decode 4 packed e4m3 bytes and accumulate dot with o[0..3].
__device__ __forceinline__ void dq4(uint u, const float* o, float& d) {
#if __has_builtin(__builtin_amdgcn_cvt_pk_f32_fp8)
    const floatx2 lo = __builtin_amdgcn_cvt_pk_f32_fp8((int)u, false);  // bytes 0,1
    const floatx2 hi = __builtin_amdgcn_cvt_pk_f32_fp8((int)u, true);   // bytes 2,3
    d = fmaf(lo.x, o[0], d);
    d = fmaf(lo.y, o[1], d);
    d = fmaf(hi.x, o[2], d);
    d = fmaf(hi.y, o[3], d);
#elif __has_builtin(__builtin_amdgcn_cvt_f32_fp8)
    d = fmaf(__builtin_amdgcn_cvt_f32_fp8((int)u, 0), o[0], d);
    d = fmaf(__builtin_amdgcn_cvt_f32_fp8((int)u, 1), o[1], d);
    d = fmaf(__builtin_amdgcn_cvt_f32_fp8((int)u, 2), o[2], d);
    d = fmaf(__builtin_amdgcn_cvt_f32_fp8((int)u, 3), o[3], d);
#else
    const float v0 = dec_h(((u << 8) & 0x8000u) | ((u << 7) & 0x3f80u));
    const float v1 = dec_h((u & 0x8000u) | ((u >> 1) & 0x3f80u));
    const float v2 = dec_h(((u >> 8) & 0x8000u) | ((u >> 9) & 0x3f80u));
    const float v3 = dec_h(((u >> 16) & 0x8000u) | ((u >> 17) & 0x3f80u));
    d = fmaf(v0, o[0], d);
    d = fmaf(v1, o[1], d);
    d = fmaf(v2, o[2], d);
    d = fmaf(v3, o[3], d);
#endif
}

// ---------- fused prep: compaction + flat fp8 convert ----------
__global__ __launch_bounds__(256) void prep_kernel(const float* __restrict__ emb,
                                                   uint* __restrict__ tbl,
                                                   const int* __restrict__ rmask,
                                                   int* __restrict__ list,
                                                   float* __restrict__ acc) {
    const int bid = blockIdx.x;
    if (bid < kCompactBlocks) {
        const int n = bid * 256 + threadIdx.x;
        if (n < kN && rmask[n]) {
            const int p = atomicAdd(reinterpret_cast<unsigned*>(&acc[2]), 1u);
            list[p] = n;
        }
    } else {
        const size_t i = ((size_t)(bid - kCompactBlocks) * 256 + threadIdx.x) * 8;
        const float4* src = reinterpret_cast<const float4*>(emb + i);
        uint2 o;
        o.x = enc4(src[0]);
        o.y = enc4(src[1]);
        reinterpret_cast<uint2*>(tbl)[i / 8] = o;
    }
}

// One wave per ACTIVE row; round-10 body (depth-4 rotating prefetch, VGPR 56).
// ATOMIC-STORM FIX (round-13 diagnosis): finish_loss's 83.6us at 7.7% VALU
// with ~8MB traffic == 6250 same-address atomicAdd(out) serialized at ~32cy
// each. Every row_loss variant rounds 0-10 ended with the SAME ~6250
// same-address atomics -> the invariant ~94us "pin" was the atomic drain
// floor, not an L2-fill cap. Tail is now a PLAIN STORE to blocksum[bid];
// a tiny single-block reduce_kernel sums the 12500 values.
__global__ __launch_bounds__(256) void row_loss_fp8(
    const float* __restrict__ emb,
    const uchar* __restrict__ tblb,
    const int* __restrict__ nbr,
    const int* __restrict__ nbrm,
    const int* __restrict__ neg,
    const int* __restrict__ list,
    const float* __restrict__ acc,
    float* __restrict__ blocksum) {
    __shared__ float s_num[4];
    const int wave = threadIdx.x >> 6;
    const int lane = threadIdx.x & 63;
    const int g = lane >> 4;
    const int t = lane & 15;
    const uint lane_off = (uint)t * 16u;

    const int cnt_active = reinterpret_cast<const int*>(acc)[2];
    const int i = blockIdx.x * 4 + wave;
    float num = 0.f;

    if (i < cnt_active) {  // wave-uniform
        const int n = list[i];

        // own row fp32 (exact), elems 16t..16t+15
        const float4* erow = reinterpret_cast<const float4*>(emb + (size_t)n * kD);
        float own[16];
#pragma unroll
        for (int j = 0; j < 4; ++j) {
            const float4 f = erow[4 * t + j];
            own[4 * j + 0] = f.x * kOwnScale;
            own[4 * j + 1] = f.y * kOwnScale;
            own[4 * j + 2] = f.z * kOwnScale;
            own[4 * j + 3] = f.w * kOwnScale;
        }

        const int* nrow = nbr + (size_t)n * kPos;
        const int* mrow = nbrm + (size_t)n * kPos;
        const int* grow = neg + (size_t)n * kNeg;

        // preload all offsets + weights
        uint off[kSlots];  // 32-bit byte offsets into the 12.8 MB table
        float w[kPos / 4];
        float cnt = 0.f;
#pragma unroll
        for (int s = 0; s < kPos / 4; ++s) {
            off[s] = ((uint)nrow[s * 4 + g] << 8) + lane_off;
            const float mf = (float)mrow[s * 4 + g];
            w[s] = mf;
            cnt += mf;
        }
#pragma unroll
        for (int s = 0; s < kNeg / 4; ++s)
            off[kPos / 4 + s] = ((uint)grow[s * 4 + g] << 8) + lane_off;

        float pos_sum = 0.f, neg_sum = 0.f;

#define LD(s) (*reinterpret_cast<const uint4*>(tblb + off[s]))
#define DO_SLOT(s, B)                                                       \
    {                                                                       \
        float d = 0.f;                                                      \
        dq4(B.x, own + 0, d);                                               \
        dq4(B.y, own + 4, d);                                               \
        dq4(B.z, own + 8, d);                                               \
        dq4(B.w, own + 12, d);                                              \
        d += __shfl_xor(d, 8);                                              \
        d += __shfl_xor(d, 4);                                              \
        d += __shfl_xor(d, 2);                                              \
        d += __shfl_xor(d, 1);                                              \
        const float sg = 1.f / (1.f + __expf(-d));                          \
        if ((s) < kPos / 4) {                                               \
            pos_sum += -__logf(sg + kEps) * w[(s) & 7];                     \
        } else {                                                            \
            neg_sum += -__logf(1.f - sg + kEps);                            \
        }                                                                   \
    }

        // prologue: 4 gathers in flight
        uint4 b0 = LD(0);
        uint4 b1 = LD(1);
        uint4 b2 = LD(2);
        uint4 b3 = LD(3);
        // steady state: decode oldest, reissue its buffer 4 slots ahead
        DO_SLOT(0, b0); b0 = LD(4);
        DO_SLOT(1, b1); b1 = LD(5);
        DO_SLOT(2, b2); b2 = LD(6);
        DO_SLOT(3, b3); b3 = LD(7);
        DO_SLOT(4, b0); b0 = LD(8);
        DO_SLOT(5, b1); b1 = LD(9);
        DO_SLOT(6, b2); b2 = LD(10);
        DO_SLOT(7, b3); b3 = LD(11);
        DO_SLOT(8, b0); b0 = LD(12);
        // drain tail
        DO_SLOT(9, b1);
        DO_SLOT(10, b2);
        DO_SLOT(11, b3);
        DO_SLOT(12, b0);
#undef LD
#undef DO_SLOT

        // combine the 4 groups (each group's 16 lanes hold identical values)
        pos_sum += __shfl_xor(pos_sum, 16);
        pos_sum += __shfl_xor(pos_sum, 32);
        neg_sum += __shfl_xor(neg_sum, 16);
        neg_sum += __shfl_xor(neg_sum, 32);
        cnt += __shfl_xor(cnt, 16);
        cnt += __shfl_xor(cnt, 32);

        if (cnt > 0.f) num = pos_sum / cnt + neg_sum / (float)kNeg;
        // cnt==0 -> NaN row in reference -> replaced by 0 -> contributes 0
    }

    if (lane == 0) s_num[wave] = num;
    __syncthreads();
    if (threadIdx.x == 0) {
        // plain store per block — NO same-address atomic (round-13 fix)
        blocksum[blockIdx.x] = s_num[0] + s_num[1] + s_num[2] + s_num[3];
    }
}

// ---------- single-block reduction of the 12500 block sums ----------
__global__ __launch_bounds__(256) void reduce_kernel(
    const float* __restrict__ blocksum,
    const float* __restrict__ acc,
    float* __restrict__ out) {
    __shared__ float s_sum[4];
    const int lane = threadIdx.x & 63;
    const int wave = threadIdx.x >> 6;
    float v = 0.f;
    for (int i = threadIdx.x; i < kRowBlocks; i += 256) v += blocksum[i];
#pragma unroll
    for (int o = 32; o >= 1; o >>= 1) v += __shfl_xor(v, o);
    if (lane == 0) s_sum[wave] = v;
    __syncthreads();
    if (threadIdx.x == 0) {
        const float tot = s_sum[0] + s_sum[1] + s_sum[2] + s_sum[3];
        out[0] = tot / (float)reinterpret_cast<const int*>(acc)[2];
    }
}

// ---------- fp32 direct fallback (tiny ws; UNCHANGED) ----------
__global__ __launch_bounds__(256) void row_loss_f32(
    const float* __restrict__ emb,
    const int* __restrict__ nbr,
    const int* __restrict__ nbrm,
    const int* __restrict__ neg,
    const int* __restrict__ rmask,
    float* __restrict__ acc) {
    __shared__ float s_num[4];
    __shared__ float s_den[4];
    const int wave = threadIdx.x >> 6;
    const int lane = threadIdx.x & 63;
    const int n = blockIdx.x * 4 + wave;
    const int g = lane >> 4;
    const int t = lane & 15;

    const float4* erow = reinterpret_cast<const float4*>(emb + (size_t)n * kD);
    float4 own4[4];
#pragma unroll
    for (int j = 0; j < 4; ++j) own4[j] = erow[j * 16 + t];

    const int* nrow = nbr + (size_t)n * kPos;
    const int* mrow = nbrm + (size_t)n * kPos;
    const int* grow = neg + (size_t)n * kNeg;

    float pos_sum = 0.f, neg_sum = 0.f, cnt = 0.f;
#pragma unroll
    for (int it = 0; it < kPos / 4; ++it) {
        const int idx = nrow[it * 4 + g];
        const float mf = (float)mrow[it * 4 + g];
        cnt += mf;
        const float4* brow = reinterpret_cast<const float4*>(emb + (size_t)idx * kD);
        float d = 0.f;
#pragma unroll
        for (int j = 0; j < 4; ++j) {
            const float4 b = brow[j * 16 + t];
            const float4 a = own4[j];
            d += a.x * b.x + a.y * b.y + a.z * b.z + a.w * b.w;
        }
        d += __shfl_xor(d, 8);
        d += __shfl_xor(d, 4);
        d += __shfl_xor(d, 2);
        d += __shfl_xor(d, 1);
        const float s = 1.f / (1.f + __expf(-d));
        pos_sum += -__logf(s + kEps) * mf;
    }
#pragma unroll
    for (int it = 0; it < kNeg / 4; ++it) {
        const int idx = grow[it * 4 + g];
        const float4* brow = reinterpret_cast<const float4*>(emb + (size_t)idx * kD);
        float d = 0.f;
#pragma unroll
        for (int j = 0; j < 4; ++j) {
            const float4 b = brow[j * 16 + t];
            const float4 a = own4[j];
            d += a.x * b.x + a.y * b.y + a.z * b.z + a.w * b.w;
        }
        d += __shfl_xor(d, 8);
        d += __shfl_xor(d, 4);
        d += __shfl_xor(d, 2);
        d += __shfl_xor(d, 1);
        const float s = 1.f / (1.f + __expf(-d));
        neg_sum += -__logf(1.f - s + kEps);
    }

    pos_sum += __shfl_xor(pos_sum, 16);
    pos_sum += __shfl_xor(pos_sum, 32);
    neg_sum += __shfl_xor(neg_sum, 16);
    neg_sum += __shfl_xor(neg_sum, 32);
    cnt += __shfl_xor(cnt, 16);
    cnt += __shfl_xor(cnt, 32);

    float num = 0.f;
    if (cnt > 0.f) num = pos_sum / cnt + neg_sum / (float)kNeg;
    const float rmf = (float)rmask[n];

    if (lane == 0) {
        s_num[wave] = num * rmf;
        s_den[wave] = rmf;
    }
    __syncthreads();
    if (threadIdx.x == 0) {
        atomicAdd(&acc[0], s_num[0] + s_num[1] + s_num[2] + s_num[3]);
        atomicAdd(&acc[1], s_den[0] + s_den[1] + s_den[2] + s_den[3]);
    }
}

__global__ void finalize_f32(const float* __restrict__ acc, float* __restrict__ out) {
    out[0] = acc[0] / acc[1];
}
}  // namespace

extern "C" void kernel_launch(void* const* d_in, const int* in_sizes, int n_in,
                              void* d_out, int out_size, void* d_ws, size_t ws_size,
                              hipStream_t stream) {
    const float* emb = (const float*)d_in[0];
    const int* nbr = (const int*)d_in[1];
    const int* nbrm = (const int*)d_in[2];
    const int* neg = (const int*)d_in[3];
    const int* rmask = (const int*)d_in[4];
    float* acc = (float*)d_ws;  // [0]=num, [1]=den, [2]=active count

    const size_t bsum_bytes = (size_t)kRowBlocks * sizeof(float);  // 50 KB
    const size_t tbl_bytes = (size_t)kN * kD;                      // 12.8 MB
    const size_t list_bytes = (size_t)kN * sizeof(int);            // 0.2 MB

    if (ws_size >= 256 + bsum_bytes + tbl_bytes + list_bytes) {
        float* bsum = (float*)((char*)d_ws + 256);
        uint* tbl = (uint*)((char*)d_ws + 256 + bsum_bytes);
        int* list = (int*)((char*)d_ws + 256 + bsum_bytes + tbl_bytes);
        hipMemsetAsync(acc, 0, 4 * sizeof(float), stream);
        prep_kernel<<<kCompactBlocks + kConvertBlocks, 256, 0, stream>>>(
            emb, tbl, rmask, list, acc);
        row_loss_fp8<<<kRowBlocks, 256, 0, stream>>>(emb, (const uchar*)tbl, nbr,
                                                     nbrm, neg, list, acc, bsum);
        reduce_kernel<<<1, 256, 0, stream>>>(bsum, acc, (float*)d_out);
    } else {
        hipMemsetAsync(acc, 0, 2 * sizeof(float), stream);
        row_loss_f32<<<kN / 4, 256, 0, stream>>>(emb, nbr, nbrm, neg, rmask, acc);
        finalize_f32<<<1, 1, 0, stream>>>(acc, (float*)d_out);
    }
}